// Round 15
// baseline (113.977 us; speedup 1.0000x reference)
//
#include <hip/hip_runtime.h>

#define NDIM 64
#define BINSHIFT 6
#define BINSZ 64           // nodes per bin
#define LCAP 3072          // per-bin edge cap (mean 2048)
#define STCAP (LCAP + 512) // sT capacity: LCAP + max align8 padding
#define EPT 8
#define PCHUNK (256 * EPT) // 2048 edges per partition chunk
#define MAXBINS 1024

typedef unsigned short ushort;
typedef short bf8 __attribute__((ext_vector_type(8)));   // 8 bf16 (4 VGPRs)
typedef float f32x4 __attribute__((ext_vector_type(4))); // MFMA acc

__device__ __forceinline__ ushort f2bf(float f) {
    unsigned u = __float_as_uint(f);
    return (ushort)((u + 0x7FFFu + ((u >> 16) & 1u)) >> 16);  // RNE
}
__device__ __forceinline__ float bflo(unsigned u) { return __uint_as_float(u << 16); }
__device__ __forceinline__ float bfhi(unsigned u) { return __uint_as_float(u & 0xFFFF0000u); }

__device__ __forceinline__ bf8 pack8(float4 a, float4 b) {
    bf8 r;
    r[0] = (short)f2bf(a.x); r[1] = (short)f2bf(a.y);
    r[2] = (short)f2bf(a.z); r[3] = (short)f2bf(a.w);
    r[4] = (short)f2bf(b.x); r[5] = (short)f2bf(b.y);
    r[6] = (short)f2bf(b.z); r[7] = (short)f2bf(b.w);
    return r;
}

// ---- Phase 1 via MFMA. reps>1 = attribution probe (idempotent).
//      Block 0 also zeroes binCursor (replaces hipMemsetAsync dispatch).
__global__ __launch_bounds__(256) void node_msg_mfma(
    const float* __restrict__ x, const float* __restrict__ W,
    ushort* __restrict__ Mb, int n_nodes,
    int* __restrict__ binCursor, int nbins, int reps)
{
    if (binCursor && blockIdx.x == 0) {
        for (int i = threadIdx.x; i < nbins; i += 256) binCursor[i] = 0;
    }

    const int lane = threadIdx.x & 63;
    const int wid  = threadIdx.x >> 6;
    const int r16  = lane & 15;
    const int g4   = lane >> 4;

    // Preload all 16 W fragments (8 dim-tiles x 2 k-halves) into VGPRs.
    bf8 bfrag[8][2];
    #pragma unroll
    for (int t = 0; t < 8; ++t) {
        #pragma unroll
        for (int h = 0; h < 2; ++h) {
            const float* wp = &W[(size_t)(t * 16 + r16) * NDIM + h * 32 + g4 * 8];
            bfrag[t][h] = pack8(*(const float4*)wp, *(const float4*)(wp + 4));
        }
    }

    int ntiles = (n_nodes + 15) >> 4;
    int stride = gridDim.x * 4;
    for (int rep = 0; rep < reps; ++rep) {
        for (int tile = blockIdx.x * 4 + wid; tile < ntiles; tile += stride) {
            int n0 = tile * 16;
            int arow = min(n0 + r16, n_nodes - 1);   // clamp for tail tile
            bf8 afrag[2];
            #pragma unroll
            for (int h = 0; h < 2; ++h) {
                const float* xp = &x[(size_t)arow * NDIM + h * 32 + g4 * 8];
                afrag[h] = pack8(*(const float4*)xp, *(const float4*)(xp + 4));
            }
            f32x4 acc[8];
            #pragma unroll
            for (int t = 0; t < 8; ++t) acc[t] = (f32x4){0.f, 0.f, 0.f, 0.f};
            #pragma unroll
            for (int h = 0; h < 2; ++h) {
                #pragma unroll
                for (int t = 0; t < 8; ++t)
                    acc[t] = __builtin_amdgcn_mfma_f32_16x16x32_bf16(
                        afrag[h], bfrag[t][h], acc[t], 0, 0, 0);
            }
            #pragma unroll
            for (int r = 0; r < 4; ++r) {
                int n = n0 + 4 * g4 + r;
                if (n < n_nodes) {
                    #pragma unroll
                    for (int t = 0; t < 4; ++t) {
                        float g = acc[t][r];
                        float e = acc[t + 4][r];
                        Mb[(size_t)n * NDIM + t * 16 + r16] =
                            f2bf(e / (1.0f + __expf(-g)));
                    }
                }
            }
        }
    }
}

// ---- Partition: scatter packed (local_s<<16|tgt) into 64-node bins ----
__global__ __launch_bounds__(256) void partition_kernel(
    const int* __restrict__ src, const int* __restrict__ tgt,
    int* __restrict__ binCursor, unsigned* __restrict__ binned,
    int n_edges, int nbins)
{
    __shared__ int h[MAXBINS];
    __shared__ int base[MAXBINS];
    const int tid = threadIdx.x;

    long long cb = (long long)blockIdx.x * PCHUNK;
    long long cs = (long long)gridDim.x * PCHUNK;
    for (; cb < n_edges; cb += cs) {
        for (int i = tid; i < nbins; i += 256) h[i] = 0;
        __syncthreads();

        unsigned pk[EPT]; ushort ps[EPT]; short pb[EPT];
        #pragma unroll
        for (int r = 0; r < EPT; ++r) {
            long long e = cb + r * 256 + tid;
            pb[r] = -1;
            if (e < n_edges) {
                int s = src[e], t = tgt[e];
                int b = s >> BINSHIFT;
                pk[r] = ((unsigned)(s & (BINSZ - 1)) << 16) | (unsigned)t;
                ps[r] = (ushort)atomicAdd(&h[b], 1);
                pb[r] = (short)b;
            }
        }
        __syncthreads();
        for (int i = tid; i < nbins; i += 256) {
            int c = h[i];
            base[i] = c ? atomicAdd(&binCursor[i], c) : 0;
        }
        __syncthreads();
        #pragma unroll
        for (int r = 0; r < EPT; ++r) {
            if (pb[r] >= 0) {
                unsigned d = (unsigned)base[pb[r]] + ps[r];
                if (d < LCAP) binned[(size_t)pb[r] * LCAP + d] = pk[r];
            }
        }
        __syncthreads();
    }
}

// ---- CSR build + gather fused; 256 threads, ~20KB LDS ----
__global__ __launch_bounds__(256) void csr_gather_kernel(
    const unsigned* __restrict__ binned, const int* __restrict__ binCursor,
    const ushort* __restrict__ Mb, const float* __restrict__ x,
    float* __restrict__ out, int n_nodes)
{
    __shared__ unsigned sE[LCAP];
    __shared__ ushort   sT[STCAP];
    __shared__ int sCnt[BINSZ];
    __shared__ int sOff[BINSZ];
    __shared__ int sCur[BINSZ];

    const int bin = blockIdx.x;
    const int tid = threadIdx.x;
    const int cnt = min(binCursor[bin], LCAP);
    const unsigned* __restrict__ be = &binned[(size_t)bin * LCAP];

    if (tid < BINSZ) sCnt[tid] = 0;
    __syncthreads();
    for (int i = tid; i < cnt; i += 256) {
        unsigned v = be[i];
        sE[i] = v;
        atomicAdd(&sCnt[v >> 16], 1);
    }
    __syncthreads();

    if (tid < 64) {
        int c = (sCnt[tid] + 7) & ~7;
        int incl = c;
        #pragma unroll
        for (int d = 1; d < 64; d <<= 1) {
            int t = __shfl_up(incl, d);
            if (tid >= d) incl += t;
        }
        int excl = incl - c;
        sOff[tid] = excl;
        sCur[tid] = excl;
    }
    __syncthreads();

    for (int i = tid; i < cnt; i += 256) {
        unsigned p = sE[i];
        int pos = atomicAdd(&sCur[p >> 16], 1);
        if (pos < STCAP) sT[pos] = (ushort)(p & 0xFFFFu);
    }
    __syncthreads();

    const int wid  = tid >> 6;
    const int lane = tid & 63;
    const int sub  = lane >> 3;
    const int sl   = lane & 7;
    #pragma unroll
    for (int r = 0; r < BINSZ / 32; ++r) {
        int ln = r * 32 + wid * 8 + sub;
        int n  = (bin << BINSHIFT) + ln;
        int c  = sCnt[ln];
        int off = sOff[ln];
        float acc[8] = {0, 0, 0, 0, 0, 0, 0, 0};
        for (int j = 0; j < c; j += 8) {
            uint4 nb = *(const uint4*)&sT[off + j];
            unsigned id[8] = { nb.x & 0xFFFFu, nb.x >> 16, nb.y & 0xFFFFu, nb.y >> 16,
                               nb.z & 0xFFFFu, nb.z >> 16, nb.w & 0xFFFFu, nb.w >> 16 };
            #pragma unroll
            for (int k = 0; k < 8; ++k) {
                if (j + k < c) {
                    uint4 v = *(const uint4*)&Mb[(size_t)id[k] * NDIM + sl * 8];
                    acc[0] += bflo(v.x); acc[1] += bfhi(v.x);
                    acc[2] += bflo(v.y); acc[3] += bfhi(v.y);
                    acc[4] += bflo(v.z); acc[5] += bfhi(v.z);
                    acc[6] += bflo(v.w); acc[7] += bfhi(v.w);
                }
            }
        }
        if (n < n_nodes) {
            size_t base = (size_t)n * NDIM + sl * 8;
            float4 x0 = *(const float4*)&x[base];
            float4 x1 = *(const float4*)&x[base + 4];
            float4 o0 = {x0.x + acc[0], x0.y + acc[1], x0.z + acc[2], x0.w + acc[3]};
            float4 o1 = {x1.x + acc[4], x1.y + acc[5], x1.z + acc[6], x1.w + acc[7]};
            *(float4*)&out[base]     = o0;
            *(float4*)&out[base + 4] = o1;
        }
    }
}

// ---------------- Fallback: atomic scatter ----------------
__global__ __launch_bounds__(256) void copy_out_kernel(
    const float* __restrict__ x, float* __restrict__ out, size_t n)
{
    size_t i = (size_t)blockIdx.x * 256 + threadIdx.x;
    size_t gs = (size_t)gridDim.x * 256;
    for (; i < n; i += gs) out[i] = x[i];
}

__global__ __launch_bounds__(256) void edge_scatter_kernel(
    const int* __restrict__ src, const int* __restrict__ tgt,
    const ushort* __restrict__ Mb, float* __restrict__ out, int n_edges)
{
    long long total = (long long)n_edges * 16;
    long long i0 = (long long)blockIdx.x * blockDim.x + threadIdx.x;
    long long gs = (long long)gridDim.x * blockDim.x;
    for (long long i = i0; i < total; i += gs) {
        int e = (int)(i >> 4);
        int q = (int)(i & 15);
        int s = src[e];
        int t = tgt[e];
        uint2 v = *(const uint2*)&Mb[(size_t)t * NDIM + q * 4];
        float* o = &out[(size_t)s * NDIM + q * 4];
        atomicAdd(o + 0, bflo(v.x));
        atomicAdd(o + 1, bfhi(v.x));
        atomicAdd(o + 2, bflo(v.y));
        atomicAdd(o + 3, bfhi(v.y));
    }
}

static inline size_t align16(size_t v) { return (v + 15) & ~(size_t)15; }

extern "C" void kernel_launch(void* const* d_in, const int* in_sizes, int n_in,
                              void* d_out, int out_size, void* d_ws, size_t ws_size,
                              hipStream_t stream)
{
    const float* x   = (const float*)d_in[0];
    const float* W   = (const float*)d_in[1];
    const int*   src = (const int*)d_in[2];
    const int*   tgt = (const int*)d_in[3];

    int n_nodes = in_sizes[0] / NDIM;
    int n_edges = in_sizes[2];
    float* out = (float*)d_out;

    int nbins = (n_nodes + BINSZ - 1) >> BINSHIFT;

    char* ws = (char*)d_ws;
    size_t off = 0;
    ushort* Mb = (ushort*)(ws + off);         off = align16(off + (size_t)n_nodes * NDIM * 2);
    int* binCursor = (int*)(ws + off);        off = align16(off + (size_t)nbins * 4);
    unsigned* binned = (unsigned*)(ws + off); off = align16(off + (size_t)nbins * LCAP * 4);
    size_t need = off + 1024;

    if (ws_size >= need && n_nodes <= 65536 && nbins <= MAXBINS) {
        // ATTRIBUTION ROUND 3: msg_mfma x8 internally (idempotent) to surface
        // its counters in top-5.  binCursor zeroing folded into block 0.
        node_msg_mfma<<<512, 256, 0, stream>>>(
            x, W, Mb, n_nodes, binCursor, nbins, 8);
        partition_kernel<<<256, 256, 0, stream>>>(
            src, tgt, binCursor, binned, n_edges, nbins);
        csr_gather_kernel<<<nbins, 256, 0, stream>>>(
            binned, binCursor, Mb, x, out, n_nodes);
    } else if (ws_size >= (size_t)n_nodes * NDIM * sizeof(ushort)) {
        node_msg_mfma<<<512, 256, 0, stream>>>(
            x, W, Mb, n_nodes, (int*)nullptr, 0, 1);
        copy_out_kernel<<<2048, 256, 0, stream>>>(x, out, (size_t)n_nodes * NDIM);
        long long total = (long long)n_edges * 16;
        edge_scatter_kernel<<<(int)((total + 255) / 256), 256, 0, stream>>>(
            src, tgt, Mb, out, n_edges);
    }
}